// Round 13
// baseline (88.151 us; speedup 1.0000x reference)
//
#include <hip/hip_runtime.h>

#define NBINS 256
#define NCOPY 32        // fallback coarse-hist copies
#define FB    2048      // fine bins over [-8, 8], width 1/128
#define FSCALE 128.0f   // FB / 16
#define FBIAS  1024.0f  // +8 * FSCALE
#define FC    4         // fine-hist LDS copies (planar)
#define P1G   1024
#define P1T   512
#define GRID2 1024
#define HTPB  512

// Order-preserving float->uint encoding (monotone increasing).
__device__ __forceinline__ unsigned enc_f(float f) {
    unsigned u = __float_as_uint(f);
    return (u & 0x80000000u) ? ~u : (u | 0x80000000u);
}
__device__ __forceinline__ float dec_f(unsigned u) {
    unsigned v = (u & 0x80000000u) ? (u & 0x7FFFFFFFu) : ~u;
    return __uint_as_float(v);
}

// ws layout (uint32 words):
//   [0 .. P1G)              per-block min (enc), plain-stored every call
//   [P1G .. 2*P1G)          per-block max (enc)
//   [2048 .. 2048+NBINS)    coarse hist bins (fallback; zeroed each call)
//   [2304 .. 2308)          mm: {enc min, enc max, flag_fine_valid, pad}
//   [2308 .. 2308+FB)       fine hist bins (zeroed each call)
//   [4608 .. 4608+P1G*FB)   pbins: per-block fine hists (big-ws path only)

__global__ void hrt_zero(unsigned* __restrict__ hist, unsigned* __restrict__ fine) {
    const int t = threadIdx.x;  // 1024
    if (t < NBINS) hist[t] = 0u;
    for (int j = t; j < FB; j += 1024) fine[j] = 0u;
}

// Single pass: exact min/max (registers) + fine histogram on fixed [-8,8].
// BIGWS=1: merge via plain stores to pbins; BIGWS=0: global atomic merge.
template <int BIGWS>
__global__ __launch_bounds__(P1T) void hrt_pass1f(
        const float4* __restrict__ in4, long n4,
        const float* __restrict__ in, long n,
        unsigned* __restrict__ pmin, unsigned* __restrict__ pmax,
        unsigned* __restrict__ fine, unsigned* __restrict__ pbins) {
    __shared__ unsigned fh[FB * FC];     // 32 KiB, planar: fh[copy*FB + ix]
    __shared__ unsigned sred[16];
    for (int j = threadIdx.x; j < FB * FC; j += P1T) fh[j] = 0u;
    __syncthreads();

    const int tid = threadIdx.x;
    const int bid = blockIdx.x;
    const int cbase = (tid & (FC - 1)) * FB;
    float lmin = INFINITY, lmax = -INFINITY;
    const long stride = (long)P1G * P1T;

    #define PROC1(v) do { \
        float _x = (v); \
        lmin = fminf(lmin, _x); lmax = fmaxf(lmax, _x); \
        int ix = (int)fmaf(_x, FSCALE, FBIAS); \
        ix = ix < 0 ? 0 : (ix > FB - 1 ? FB - 1 : ix); \
        atomicAdd(&fh[cbase + ix], 1u); } while (0)
    #define PROC4(q) do { PROC1((q).x); PROC1((q).y); PROC1((q).z); PROC1((q).w); } while (0)

    long i = (long)bid * P1T + tid;
    for (; i + 3 * stride < n4; i += 4 * stride) {
        float4 a = in4[i];
        float4 b = in4[i + stride];
        float4 c = in4[i + 2 * stride];
        float4 d = in4[i + 3 * stride];
        PROC4(a); PROC4(b); PROC4(c); PROC4(d);
    }
    for (; i < n4; i += stride) { float4 a = in4[i]; PROC4(a); }
    for (long j = n4 * 4 + (long)bid * P1T + tid; j < n; j += stride) PROC1(in[j]);
    #undef PROC1
    #undef PROC4

    unsigned emin = enc_f(lmin), emax = enc_f(lmax);
    #pragma unroll
    for (int off = 32; off > 0; off >>= 1) {
        emin = min(emin, (unsigned)__shfl_down((int)emin, off));
        emax = max(emax, (unsigned)__shfl_down((int)emax, off));
    }
    const int wave = tid >> 6, lane = tid & 63;
    if (lane == 0) { sred[wave] = emin; sred[8 + wave] = emax; }
    __syncthreads();   // also guarantees all fh atomics are complete
    if (tid == 0) {
        unsigned m0 = sred[0], m1 = sred[8];
        #pragma unroll
        for (int w = 1; w < P1T / 64; ++w) {
            m0 = min(m0, sred[w]);
            m1 = max(m1, sred[8 + w]);
        }
        pmin[bid] = m0;   // plain stores; kernel boundary publishes them
        pmax[bid] = m1;
    }
    // merge fine LDS hist
    if (BIGWS) {
        // plain coalesced stores to this block's private region (no atomics)
        unsigned* dst = pbins + (long)bid * FB;
        for (int b = tid; b < FB; b += P1T) {
            unsigned t = fh[b] + fh[FB + b] + fh[2 * FB + b] + fh[3 * FB + b];
            dst[b] = t;   // always store: region fully rewritten each call
        }
    } else {
        for (int b = tid; b < FB; b += P1T) {
            unsigned t = fh[b] + fh[FB + b] + fh[2 * FB + b] + fh[3 * FB + b];
            if (t) atomicAdd(&fine[b], t);
        }
    }
}

// Big-ws path: reduce pbins (P1G x FB) into fine[], and (block 8) reduce the
// per-block min/max partials into mm.
__global__ __launch_bounds__(512) void hrt_reduce(
        const unsigned* __restrict__ pbins,
        const unsigned* __restrict__ pmin, const unsigned* __restrict__ pmax,
        unsigned* __restrict__ fine, unsigned* __restrict__ mm) {
    const int tid = threadIdx.x;   // 512
    const int bid = blockIdx.x;    // 9 blocks: 0..7 reduce slices, 8 = minmax
    if (bid < 8) {
        // thread t owns bin-quad t (bins 4t..4t+3); rows bid*128..bid*128+127
        const uint4* p4 = (const uint4*)pbins;   // row j, quad t -> p4[j*512 + t]
        unsigned s0 = 0, s1 = 0, s2 = 0, s3 = 0;
        long base = (long)bid * 128 * 512 + tid;
        for (int j = 0; j < 128; ++j) {
            uint4 v = p4[base + (long)j * 512];
            s0 += v.x; s1 += v.y; s2 += v.z; s3 += v.w;
        }
        if (s0) atomicAdd(&fine[tid * 4 + 0], s0);
        if (s1) atomicAdd(&fine[tid * 4 + 1], s1);
        if (s2) atomicAdd(&fine[tid * 4 + 2], s2);
        if (s3) atomicAdd(&fine[tid * 4 + 3], s3);
    } else {
        __shared__ unsigned sred[16];
        const int wave = tid >> 6, lane = tid & 63;
        uint2 a = ((const uint2*)pmin)[tid];   // 512 x 2 = 1024 words
        uint2 b = ((const uint2*)pmax)[tid];
        unsigned gmin = min(a.x, a.y);
        unsigned gmax = max(b.x, b.y);
        #pragma unroll
        for (int off = 32; off > 0; off >>= 1) {
            gmin = min(gmin, (unsigned)__shfl_down((int)gmin, off));
            gmax = max(gmax, (unsigned)__shfl_down((int)gmax, off));
        }
        if (lane == 0) { sred[wave] = gmin; sred[8 + wave] = gmax; }
        __syncthreads();
        if (tid == 0) {
            unsigned m0 = sred[0], m1 = sred[8];
            #pragma unroll
            for (int w = 1; w < 8; ++w) {
                m0 = min(m0, sred[w]);
                m1 = max(m1, sred[8 + w]);
            }
            mm[0] = m0;
            mm[1] = m1;
            float tmin = dec_f(m0), tmax = dec_f(m1);
            mm[2] = (tmin >= -8.0f && tmax <= 8.0f) ? 1u : 0u;
        }
    }
}

// Small-ws fallback: standalone minmax reduce (round-12 hrt_mid).
__global__ void hrt_mid(const unsigned* __restrict__ pmin,
                        const unsigned* __restrict__ pmax,
                        unsigned* __restrict__ mm) {
    __shared__ unsigned sred[16];
    const int tid = threadIdx.x;           // 512 threads
    const int wave = tid >> 6, lane = tid & 63;
    uint2 a = ((const uint2*)pmin)[tid];
    uint2 b = ((const uint2*)pmax)[tid];
    unsigned gmin = min(a.x, a.y);
    unsigned gmax = max(b.x, b.y);
    #pragma unroll
    for (int off = 32; off > 0; off >>= 1) {
        gmin = min(gmin, (unsigned)__shfl_down((int)gmin, off));
        gmax = max(gmax, (unsigned)__shfl_down((int)gmax, off));
    }
    if (lane == 0) { sred[wave] = gmin; sred[8 + wave] = gmax; }
    __syncthreads();
    if (tid == 0) {
        unsigned m0 = sred[0], m1 = sred[8];
        #pragma unroll
        for (int w = 1; w < 8; ++w) {
            m0 = min(m0, sred[w]);
            m1 = max(m1, sred[8 + w]);
        }
        mm[0] = m0;
        mm[1] = m1;
        float tmin = dec_f(m0), tmax = dec_f(m1);
        mm[2] = (tmin >= -8.0f && tmax <= 8.0f) ? 1u : 0u;
    }
}

// Fallback exact coarse histogram (round-10 proven). Early-exits when the
// fine histogram covers the data range.
__global__ __launch_bounds__(HTPB) void hrt_histfb(
        const float4* __restrict__ in4, long n4,
        const float* __restrict__ in, long n,
        const unsigned* __restrict__ mm,
        unsigned* __restrict__ hist) {
    if (mm[2] != 0u) return;   // fine path valid: nothing to do
    __shared__ unsigned lh[NBINS * NCOPY];
    for (int i = threadIdx.x; i < NBINS * NCOPY; i += HTPB) lh[i] = 0u;
    __syncthreads();
    const float tmin = dec_f(mm[0]);
    const float tmax = dec_f(mm[1]);
    const float scale = (float)NBINS / (tmax - tmin);
    const float bias = -tmin * scale;
    const int copy = threadIdx.x & (NCOPY - 1);
    const long tid = (long)blockIdx.x * HTPB + threadIdx.x;
    const long stride = (long)GRID2 * HTPB;

    #define HIST1(v)  do { \
        int ix = (int)fmaf((v), scale, bias); \
        ix = ix < 0 ? 0 : (ix > NBINS - 1 ? NBINS - 1 : ix); \
        atomicAdd(&lh[ix * NCOPY + copy], 1u); } while (0)
    #define HIST4(q)  do { HIST1((q).x); HIST1((q).y); HIST1((q).z); HIST1((q).w); } while (0)

    long i = tid;
    for (; i + 3 * stride < n4; i += 4 * stride) {
        float4 a = in4[i];
        float4 b = in4[i + stride];
        float4 c = in4[i + 2 * stride];
        float4 d = in4[i + 3 * stride];
        HIST4(a); HIST4(b); HIST4(c); HIST4(d);
    }
    for (; i < n4; i += stride) { float4 a = in4[i]; HIST4(a); }
    for (long j = n4 * 4 + tid; j < n; j += stride) HIST1(in[j]);
    #undef HIST1
    #undef HIST4
    __syncthreads();
    const int lane = threadIdx.x & 63;
    for (int b = threadIdx.x; b < NBINS; b += HTPB) {
        unsigned t = 0;
        #pragma unroll
        for (int c = 0; c < NCOPY; ++c) {
            int cc = (c + lane) & (NCOPY - 1);
            t += lh[b * NCOPY + cc];
        }
        if (t) atomicAdd(&hist[b], t);
    }
}

// Finalize: fine path maps the 2048-bin fixed-range histogram onto the 256
// reference bins via edge interpolation; fallback path uses coarse bins.
__global__ void hrt_fin(const unsigned* __restrict__ hist,
                        const unsigned* __restrict__ fine,
                        const unsigned* __restrict__ mm,
                        float* __restrict__ out) {
    __shared__ unsigned fu[FB];
    __shared__ double ssum[NBINS];
    __shared__ double sexc[NBINS];
    __shared__ double ccum[NBINS];
    __shared__ double sdtot;
    const int tid = threadIdx.x;   // 256
    const float tmin = dec_f(mm[0]);
    const float tmax = dec_f(mm[1]);

    if (mm[2] != 0u) {
        // ---- fine path ----
        double s = 0.0;
        #pragma unroll
        for (int k = 0; k < 8; ++k) {
            unsigned v = fine[tid * 8 + k];
            fu[tid * 8 + k] = v;
            s += (double)v;
        }
        ssum[tid] = s;
        __syncthreads();
        if (tid == 0) {
            double run = 0.0;
            for (int g = 0; g < NBINS; ++g) { sexc[g] = run; run += ssum[g]; }
            sdtot = run;
        }
        __syncthreads();
        const double total = sdtot;
        const double stepd = ((double)tmax - (double)tmin) / 256.0;
        {
            double F;
            if (tid == 255) {
                F = total;
            } else {
                double e = (double)tmin + stepd * (double)(tid + 1);
                double p = (e + 8.0) * 128.0;     // position in fine-bin space
                if (p < 0.0) p = 0.0;
                if (p > (double)FB) p = (double)FB;
                int ii = (int)p;
                double frac = p - (double)ii;
                if (ii >= FB) { ii = FB - 1; frac = 1.0; }
                double cumi = sexc[ii >> 3];
                for (int k = (ii & ~7); k < ii; ++k) cumi += (double)fu[k];
                F = cumi + frac * (double)fu[ii];
            }
            ccum[tid] = F;
        }
        __syncthreads();
        if (tid == 0) {
            double tl = total * 0.005;
            double tu = total * 0.995;
            int lower = -1, upper = -1;
            for (int b = 0; b < NBINS; ++b) {
                if (lower < 0 && ccum[b] > tl) lower = b;
                if (upper < 0 && ccum[b] > tu) upper = b;
            }
            if (lower < 0) lower = 0;
            if (upper < 0) upper = 0;
            out[0] = (float)((double)tmin + stepd * (double)lower);
            out[1] = (float)((double)tmin + stepd * (double)upper);
        }
    } else {
        // ---- fallback coarse path ----
        if (tid == 0) {
            float total = 0.0f;
            for (int i = 0; i < NBINS; ++i) total += (float)hist[i];
            float tl = total * (1.0f - 0.99f) / 2.0f;
            float tu = total * (1.0f + 0.99f) / 2.0f;
            int lower = -1, upper = -1;
            float cum = 0.0f;
            for (int i = 0; i < NBINS; ++i) {
                cum += (float)hist[i];
                if (lower < 0 && cum > tl) lower = i;
                if (upper < 0 && cum > tu) upper = i;
            }
            if (lower < 0) lower = 0;
            if (upper < 0) upper = 0;
            float step = (tmax - tmin) / (float)NBINS;
            out[0] = tmin + step * (float)lower;
            out[1] = tmin + step * (float)upper;
        }
    }
}

extern "C" void kernel_launch(void* const* d_in, const int* in_sizes, int n_in,
                              void* d_out, int out_size, void* d_ws, size_t ws_size,
                              hipStream_t stream) {
    const float* in = (const float*)d_in[0];
    long n = (long)in_sizes[0];
    long n4 = n / 4;
    unsigned* ws = (unsigned*)d_ws;
    float* out = (float*)d_out;

    unsigned* pmin = ws;
    unsigned* pmax = ws + P1G;
    unsigned* hist = ws + 2048;
    unsigned* mm   = ws + 2304;
    unsigned* fine = ws + 2308;
    unsigned* pbins = ws + 4608;
    const size_t need = (size_t)4608 * 4 + (size_t)P1G * FB * 4;

    hrt_zero<<<1, 1024, 0, stream>>>(hist, fine);
    if (ws_size >= need) {
        hrt_pass1f<1><<<P1G, P1T, 0, stream>>>((const float4*)in, n4, in, n,
                                               pmin, pmax, fine, pbins);
        hrt_reduce<<<9, 512, 0, stream>>>(pbins, pmin, pmax, fine, mm);
    } else {
        hrt_pass1f<0><<<P1G, P1T, 0, stream>>>((const float4*)in, n4, in, n,
                                               pmin, pmax, fine, pbins);
        hrt_mid<<<1, 512, 0, stream>>>(pmin, pmax, mm);
    }
    hrt_histfb<<<GRID2, HTPB, 0, stream>>>((const float4*)in, n4, in, n, mm, hist);
    hrt_fin<<<1, 256, 0, stream>>>(hist, fine, mm, out);
}